// Round 15
// baseline (99.741 us; speedup 1.0000x reference)
//
#include <hip/hip_runtime.h>

#define N 256
#define NN 65536

typedef __attribute__((ext_vector_type(8))) __bf16 bf16x8;
typedef __attribute__((ext_vector_type(4))) __bf16 bf16x4v;
typedef __attribute__((ext_vector_type(4))) float f32x4;

// ---- workspace layout (float offsets) ----
#define F_PART   0u          // [512 blocks][256 b][16 ml] yadj partials (8MB)
#define F_CSPART 2097152u    // [16 mg][65536 jk] colsum partials (4MB)
#define F_WSC    3145728u    // [256]
#define F_CSB    3145984u    // 65536 bf16 (32768 floats): CS[j][k]
#define F_SFULL  3178752u    // [65536] f32
#define F_YADJ   3244288u    // [65536] f32
#define F_PROBE  4194304u    // probe dump area (8MB)
#define WS_FLOATS 6291456u   // gate: 24MB (ws is ~256MB per fill evidence)

static __device__ __forceinline__ f32x4 mfma16(bf16x8 a, bf16x8 b, f32x4 c) {
  return __builtin_amdgcn_mfma_f32_16x16x32_bf16(a, b, c, 0, 0, 0);
}
static __device__ __forceinline__ bf16x4v pack4(float4 v) {
  bf16x4v r;
  r[0] = (__bf16)v.x; r[1] = (__bf16)v.y; r[2] = (__bf16)v.z; r[3] = (__bf16)v.w;
  return r;
}
static __device__ __forceinline__ bf16x8 pack8(float4 a, float4 b) {
  bf16x8 r;
  r[0] = (__bf16)a.x; r[1] = (__bf16)a.y; r[2] = (__bf16)a.z; r[3] = (__bf16)a.w;
  r[4] = (__bf16)b.x; r[5] = (__bf16)b.y; r[6] = (__bf16)b.z; r[7] = (__bf16)b.w;
  return r;
}

// ============================================================================
// kprobe<V>: BISECTION PROBES on the exact v14 skeleton (grid 512, 512 thr,
//   64KB slab stage, 8 n-step MFMA compute).
//   V=0: dummy af (VALU-built) + stage + compute + single dump store.
//   V=1: V0 + the REAL ctx->af prologue (the only added piece).
//   kbig(v14, below) = V1 + xl/yadj/CS/wsc/epilogue. Three-point bisection.
// ============================================================================
template<int V>
__global__ void __launch_bounds__(512) kprobe(
    const float* __restrict__ ctx, const float* __restrict__ clw,
    float* __restrict__ dump)
{
  extern __shared__ char smem[];
  const int t = threadIdx.x;
  const int mg = blockIdx.x >> 5, s = blockIdx.x & 31;
  const int m0 = mg * 16, n0 = s * 8;
  const int lane = t & 63, w = t >> 6;
  const int wb = w * 32;
  const int l15 = lane & 15, lhi = lane >> 4;
  const float4* clwf4 = (const float4*)clw;

  bf16x8 af[2][8];
  if constexpr (V == 0) {
#pragma unroll
    for (int i = 0; i < 2; ++i)
#pragma unroll
      for (int c = 0; c < 8; ++c)
#pragma unroll
        for (int e = 0; e < 8; ++e)
          af[i][c][e] = (__bf16)(float)((lane + i + c + e) & 7);
  } else {
#pragma unroll
    for (int i = 0; i < 2; ++i)
#pragma unroll
      for (int c = 0; c < 8; ++c) {
        const float4* p = (const float4*)(ctx + (wb + i * 16 + l15) * N +
                                          c * 32 + lhi * 8);
        af[i][c] = pack8(p[0], p[1]);
      }
  }
  {
    float4 val[16];
#pragma unroll
    for (int r = 0; r < 16; ++r)
      val[r] = clwf4[(size_t)(m0 + r) * 16384 + n0 * 64 + t];
#pragma unroll
    for (int r = 0; r < 16; ++r)
      *(bf16x4v*)(smem + r * 4096 + ((t * 8) ^ ((r & 7) << 4))) = pack4(val[r]);
  }
  __syncthreads();
  const f32x4 zero = {0.f, 0.f, 0.f, 0.f};
  f32x4 acc[2];
  acc[0] = zero; acc[1] = zero;
#pragma unroll
  for (int n = 0; n < 8; ++n) {
#pragma unroll
    for (int c = 0; c < 8; ++c) {
      const int kbyte = (c * 64 + lhi * 16) ^ ((l15 & 7) << 4);
      bf16x8 bf = *(const bf16x8*)(smem + l15 * 4096 + n * 512 + kbyte);
      acc[0] = mfma16(af[0][c], bf, acc[0]);
      acc[1] = mfma16(af[1][c], bf, acc[1]);
    }
  }
  const size_t base = (size_t)blockIdx.x * 4096 + (size_t)t * 8;
#pragma unroll
  for (int r = 0; r < 4; ++r) {
    dump[base + r] = acc[0][r];
    dump[base + 4 + r] = acc[1][r];
  }
}

// ============================================================================
// kbig v14 (REAL, unchanged): grid 512 = mg(16) x s(32); 512 thr.
// ============================================================================
__global__ void __launch_bounds__(512) kbig(
    const float* __restrict__ X, const float* __restrict__ ctx,
    const float* __restrict__ W, const float* __restrict__ clb,
    const float* __restrict__ clw, float* __restrict__ ws)
{
  extern __shared__ char smem[];
  float* xl  = (float*)(smem + 65536);
  float* red = (float*)smem;
  const int t = threadIdx.x;
  const int mg = blockIdx.x >> 5, s = blockIdx.x & 31;
  const int m0 = mg * 16, n0 = s * 8;

  const int lane = t & 63, w = t >> 6;
  const int wb = w * 32;
  const int l15 = lane & 15, lhi = lane >> 4;
  const float4* clwf4 = (const float4*)clw;

  bf16x8 af[2][8];
#pragma unroll
  for (int i = 0; i < 2; ++i)
#pragma unroll
    for (int c = 0; c < 8; ++c) {
      const float4* p = (const float4*)(ctx + (wb + i * 16 + l15) * N +
                                        c * 32 + lhi * 8);
      af[i][c] = pack8(p[0], p[1]);
    }
  if (t < 256) {
    const float4* xp = (const float4*)(X + t * N + n0);
    const float4 x0 = xp[0], x1 = xp[1];
    xl[0 * 256 + t] = x0.x; xl[1 * 256 + t] = x0.y;
    xl[2 * 256 + t] = x0.z; xl[3 * 256 + t] = x0.w;
    xl[4 * 256 + t] = x1.x; xl[5 * 256 + t] = x1.y;
    xl[6 * 256 + t] = x1.z; xl[7 * 256 + t] = x1.w;
  }

  float4 cso = {0.f, 0.f, 0.f, 0.f};
  {
    float4 val[16];
#pragma unroll
    for (int r = 0; r < 16; ++r)
      val[r] = clwf4[(size_t)(m0 + r) * 16384 + n0 * 64 + t];
#pragma unroll
    for (int r = 0; r < 16; ++r) {
      cso.x += val[r].x; cso.y += val[r].y;
      cso.z += val[r].z; cso.w += val[r].w;
      *(bf16x4v*)(smem + r * 4096 + ((t * 8) ^ ((r & 7) << 4))) = pack4(val[r]);
    }
  }
  __syncthreads();

  const f32x4 zero = {0.f, 0.f, 0.f, 0.f};
  f32x4 acc[2];
  acc[0] = zero; acc[1] = zero;

#pragma unroll
  for (int n = 0; n < 8; ++n) {
    f32x4 h[2];
    h[0] = zero; h[1] = zero;
#pragma unroll
    for (int c = 0; c < 8; ++c) {
      const int kbyte = (c * 64 + lhi * 16) ^ ((l15 & 7) << 4);
      bf16x8 bf = *(const bf16x8*)(smem + l15 * 4096 + n * 512 + kbyte);
      h[0] = mfma16(af[0][c], bf, h[0]);
      h[1] = mfma16(af[1][c], bf, h[1]);
    }
#pragma unroll
    for (int r = 0; r < 4; ++r) {
      h[0][r] *= xl[n * 256 + wb + lhi * 4 + r];
      h[1][r] *= xl[n * 256 + wb + 16 + lhi * 4 + r];
      acc[0][r] += h[0][r];
      acc[1][r] += h[1][r];
    }
  }

  *(float4*)(ws + F_CSPART + mg * 65536u + s * 2048 + t * 4) = cso;

  const size_t base = (size_t)blockIdx.x * 4096;
#pragma unroll
  for (int i = 0; i < 2; ++i)
#pragma unroll
    for (int r = 0; r < 4; ++r)
      ws[F_PART + base + (size_t)(wb + i * 16 + lhi * 4 + r) * 16 + l15] =
          acc[i][r];

  if (mg == 0) {
    __syncthreads();
    if (t < 256) {
      const float4* wp = (const float4*)(W + t * N + s * 8);
      const float4* cp = (const float4*)(clb + t * N + s * 8);
      const float4 a0 = wp[0], a1 = wp[1], c0 = cp[0], c1 = cp[1];
      red[0 * 256 + t] = a0.x + c0.x; red[1 * 256 + t] = a0.y + c0.y;
      red[2 * 256 + t] = a0.z + c0.z; red[3 * 256 + t] = a0.w + c0.w;
      red[4 * 256 + t] = a1.x + c1.x; red[5 * 256 + t] = a1.y + c1.y;
      red[6 * 256 + t] = a1.z + c1.z; red[7 * 256 + t] = a1.w + c1.w;
    }
    __syncthreads();
    if (t < 64) {
      const int jj = t >> 3, seg = t & 7;
      float v = 0.f;
#pragma unroll
      for (int i = 0; i < 32; ++i) v += red[jj * 256 + seg * 32 + i];
      v += __shfl_xor(v, 1);
      v += __shfl_xor(v, 2);
      v += __shfl_xor(v, 4);
      if (seg == 0) ws[F_WSC + s * 8 + jj] = v;
    }
  }
}

// ============================================================================
// kred: yadj reduce over 32 s-slots; CS = sum over 16 mg -> bf16 CSB
// ============================================================================
__global__ void __launch_bounds__(256) kred(float* __restrict__ ws)
{
  const int o = blockIdx.x * 256 + threadIdx.x;
  const int b = o >> 8, m = o & 255;
  const int mgg = m >> 4, ml = m & 15;
  const size_t pb = F_PART + (size_t)(mgg * 32) * 4096 + (size_t)b * 16 + ml;
  float y = 0.f;
#pragma unroll
  for (int si = 0; si < 32; ++si)
    y += ws[pb + (size_t)si * 4096];
  ws[F_YADJ + o] = y;
  float cv = 0.f;
#pragma unroll
  for (int g = 0; g < 16; ++g)
    cv += ws[F_CSPART + g * 65536u + o];
  ((__bf16*)(ws + F_CSB))[o] = (__bf16)cv;
}

// ============================================================================
// kred2: SF[b,j] = wsc[j] + sum_k ctx[b,k]*CS[j,k]
// ============================================================================
__global__ void __launch_bounds__(256) kred2(
    const float* __restrict__ ctx, float* __restrict__ ws)
{
  const int t = threadIdx.x, blk = blockIdx.x;
  const int b0 = (blk >> 3) * 32, j0 = (blk & 7) * 32;
  const int lane = t & 63, w = t >> 6;
  const int l15 = lane & 15, lhi = lane >> 4;
  const int wqb = (w >> 1) * 16, wqj = (w & 1) * 16;
  const char* csb = (const char*)(ws + F_CSB);

  f32x4 accq = {0.f, 0.f, 0.f, 0.f};
#pragma unroll
  for (int c = 0; c < 8; ++c) {
    const float4* p = (const float4*)(ctx + (b0 + wqb + l15) * N +
                                      c * 32 + lhi * 8);
    bf16x8 a = pack8(p[0], p[1]);
    bf16x8 b = *(const bf16x8*)(csb + (j0 + wqj + l15) * 512 +
                                c * 64 + lhi * 16);
    accq = mfma16(a, b, accq);
  }
  const int j = j0 + wqj + l15;
  const float wscv = ws[F_WSC + j];
#pragma unroll
  for (int r = 0; r < 4; ++r) {
    const int b = b0 + wqb + lhi * 4 + r;
    ws[F_SFULL + b * N + j] = accq[r] + wscv;
  }
}

// ============================================================================
// kfin: unchanged
// ============================================================================
__global__ void __launch_bounds__(256) kfin(
    const float* __restrict__ X, const float* __restrict__ ctx,
    const float* __restrict__ W, const float* __restrict__ clb,
    const float* __restrict__ A, const float* __restrict__ scale,
    const int* __restrict__ tptr, float* __restrict__ out,
    float* __restrict__ ws)
{
  extern __shared__ char smem[];
  const int t = threadIdx.x, blk = blockIdx.x;
  const int b0 = (blk >> 3) * 32, k0 = (blk & 7) * 32;
  {
    const int row = t >> 3, q = t & 7;
    const int sw = (row & 7) << 4;
    const float4* sp = (const float4*)(ws + F_SFULL + (b0 + row) * N);
    const float4* xp = (const float4*)(X + (b0 + row) * N);
    const float4* wp = (const float4*)(W + (k0 + row) * N);
    const float4* cp = (const float4*)(clb + (k0 + row) * N);
#pragma unroll
    for (int i = 0; i < 8; ++i) {
      const int f4 = q * 8 + i;
      const int off = row * 512 + ((f4 * 8) ^ sw);
      *(bf16x4v*)(smem + off) = pack4(sp[f4]);
      *(bf16x4v*)(smem + 16384 + off) = pack4(xp[f4]);
      const float4 wv = wp[f4], cv = cp[f4];
      float4 s2;
      s2.x = wv.x + cv.x; s2.y = wv.y + cv.y;
      s2.z = wv.z + cv.z; s2.w = wv.w + cv.w;
      *(bf16x4v*)(smem + 49152 + off) = pack4(s2);
    }
    const float4* ap = (const float4*)(A + t * N + k0);
    char* at = smem + 32768;
#pragma unroll
    for (int i = 0; i < 8; ++i) {
      const float4 v = ap[i];
      const int kk = i * 4;
      *(__bf16*)(at + (kk + 0) * 512 + ((t * 2) ^ (((kk + 0) & 7) << 4))) = (__bf16)v.x;
      *(__bf16*)(at + (kk + 1) * 512 + ((t * 2) ^ (((kk + 1) & 7) << 4))) = (__bf16)v.y;
      *(__bf16*)(at + (kk + 2) * 512 + ((t * 2) ^ (((kk + 2) & 7) << 4))) = (__bf16)v.z;
      *(__bf16*)(at + (kk + 3) * 512 + ((t * 2) ^ (((kk + 3) & 7) << 4))) = (__bf16)v.w;
    }
  }
  __syncthreads();
  const int lane = t & 63, w = t >> 6;
  const int l15 = lane & 15, lhi = lane >> 4;
  const int wqb = (w >> 1) * 16, wqk = (w & 1) * 16;
  const int swz = (l15 & 7) << 4;
  f32x4 accd = {0.f, 0.f, 0.f, 0.f}, accw = {0.f, 0.f, 0.f, 0.f};
#pragma unroll
  for (int c = 0; c < 8; ++c) {
    const int kb = c * 64 + lhi * 16;
    bf16x8 as  = *(const bf16x8*)(smem + (wqb + l15) * 512 + (kb ^ swz));
    bf16x8 aat = *(const bf16x8*)(smem + 32768 + (wqk + l15) * 512 + (kb ^ swz));
    bf16x8 ax  = *(const bf16x8*)(smem + 16384 + (wqb + l15) * 512 + (kb ^ swz));
    bf16x8 awc = *(const bf16x8*)(smem + 49152 + (wqk + l15) * 512 + (kb ^ swz));
    accd = mfma16(as, aat, accd);
    accw = mfma16(ax, awc, accw);
  }
  const float sc = scale[0];
  const float tf = (float)(*tptr);
  const float c1 = tf / (tf + 1.f), c2 = 1.f / (tf + 1.f);
#pragma unroll
  for (int r = 0; r < 4; ++r) {
    const int b = b0 + wqb + lhi * 4 + r, k = k0 + wqk + l15;
    const int idx = b * N + k;
    const float xv = X[idx];
    out[idx] = sc * (xv * accd[r] - accw[r] - ws[F_YADJ + idx]);
    out[NN + idx] = ctx[idx] * c1 + xv * c2;
  }
}

extern "C" void kernel_launch(void* const* d_in, const int* in_sizes, int n_in,
                              void* d_out, int out_size, void* d_ws, size_t ws_size,
                              hipStream_t stream)
{
  (void)in_sizes; (void)n_in; (void)out_size;
  const float* X     = (const float*)d_in[0];
  const float* ctx   = (const float*)d_in[1];
  const float* W     = (const float*)d_in[2];
  const float* scale = (const float*)d_in[3];
  const float* A     = (const float*)d_in[4];
  const float* clw   = (const float*)d_in[5];
  const float* clb   = (const float*)d_in[6];
  const int*   tptr  = (const int*)d_in[7];
  float* out = (float*)d_out;
  float* ws  = (float*)d_ws;

  if (ws_size < (size_t)WS_FLOATS * sizeof(float)) return;

  (void)hipFuncSetAttribute((const void*)kprobe<0>,
                            hipFuncAttributeMaxDynamicSharedMemorySize, 65536);
  (void)hipFuncSetAttribute((const void*)kprobe<1>,
                            hipFuncAttributeMaxDynamicSharedMemorySize, 65536);
  (void)hipFuncSetAttribute((const void*)kbig,
                            hipFuncAttributeMaxDynamicSharedMemorySize, 73728);
  (void)hipFuncSetAttribute((const void*)kfin,
                            hipFuncAttributeMaxDynamicSharedMemorySize, 65536);

  // ---- bisection probes (dump -> F_PROBE scratch) ----
  float* dump = ws + F_PROBE;
  kprobe<0><<<512, 512, 65536, stream>>>(ctx, clw, dump);  // core only
  kprobe<1><<<512, 512, 65536, stream>>>(ctx, clw, dump);  // + ctx af prologue

  // ---- real pipeline ----
  kbig<<<512, 512, 73728, stream>>>(X, ctx, W, clb, clw, ws);
  kred<<<256, 256, 0, stream>>>(ws);
  kred2<<<64, 256, 0, stream>>>(ctx, ws);
  kfin<<<64, 256, 65536, stream>>>(X, ctx, W, clb, A, scale, tptr, out, ws);
}

// Round 16
// 69.577 us; speedup vs baseline: 1.4335x; 1.4335x over previous
//
#include <hip/hip_runtime.h>

#define N 256
#define NN 65536

typedef __attribute__((ext_vector_type(8))) __bf16 bf16x8;
typedef __attribute__((ext_vector_type(4))) __bf16 bf16x4v;
typedef __attribute__((ext_vector_type(4))) float f32x4;

// ---- workspace layout (float offsets); ws = 256 MiB (fill evidence) ----
#define F_CLWB   0u          // 8,388,608 f  : clw as bf16 (32MB image)
#define F_CSPART 8388608u    // [16][65536]  : CS colsum partials (4MB)
#define F_PART   9437184u    // [512 blk][256 b][16 ml] yadj partials (8MB)
#define F_WSC    11534336u   // [256]
#define F_CSB    11534592u   // 65536 bf16 (32768 f): CS[j][k]
#define F_SFULL  11567360u   // [65536]
#define F_YADJ   11632896u   // [65536]
#define WS_FLOATS 11698432u  // ~47MB gate

static __device__ __forceinline__ f32x4 mfma16(bf16x8 a, bf16x8 b, f32x4 c) {
  return __builtin_amdgcn_mfma_f32_16x16x32_bf16(a, b, c, 0, 0, 0);
}
static __device__ __forceinline__ bf16x4v pack4(float4 v) {
  bf16x4v r;
  r[0] = (__bf16)v.x; r[1] = (__bf16)v.y; r[2] = (__bf16)v.z; r[3] = (__bf16)v.w;
  return r;
}
static __device__ __forceinline__ bf16x8 pack8(float4 a, float4 b) {
  bf16x8 r;
  r[0] = (__bf16)a.x; r[1] = (__bf16)a.y; r[2] = (__bf16)a.z; r[3] = (__bf16)a.w;
  r[4] = (__bf16)b.x; r[5] = (__bf16)b.y; r[6] = (__bf16)b.z; r[7] = (__bf16)b.w;
  return r;
}

// ============================================================================
// kcvt: PURE STREAM (m13 copy pattern). grid 1024 x 256 thr, 16 f4/thread,
//   grid-stride: thread g handles flat f4 idx {i*262144+g} (coalesced).
//   clw f32 -> bf16 image at F_CLWB + fused CS colsum: thread g's 16 samples
//   share one nk (stride 1,048,576 floats = 16 m), m = i*16+(g>>14) ->
//   partial slot (g>>14) of CSPART[16][65536]. Tiny regs -> 8 waves/SIMD.
// ============================================================================
__global__ void __launch_bounds__(256) kcvt(
    const float* __restrict__ clw, float* __restrict__ ws)
{
  const int g = blockIdx.x * 256 + threadIdx.x;   // [0, 262144)
  const float4* in = (const float4*)clw;
  bf16x4v* outb = (bf16x4v*)(ws + F_CLWB);
  float4 cso = {0.f, 0.f, 0.f, 0.f};
#pragma unroll
  for (int i = 0; i < 16; ++i) {
    const float4 v = in[(size_t)i * 262144 + g];
    cso.x += v.x; cso.y += v.y; cso.z += v.z; cso.w += v.w;
    outb[(size_t)i * 262144 + g] = pack4(v);
  }
  *(float4*)(ws + F_CSPART + (size_t)(g >> 14) * 65536 +
             (size_t)(g & 16383) * 4) = cso;
}

// ============================================================================
// kbig v15: v14 geometry (grid 512 = mg(16) x s(32), 512 thr, 16m x 8n x 256k
//   slab) but consumes the BF16 image: half the bytes (64KB/block), L3-hot
//   after kcvt, no f32->bf16 cvt, no CS work. Stage loads issue FIRST.
// LDS: buf 64KB @0 (16 rows x 4KB, XOR-swizzled) | xl[8][256]f32 @65536
//      (73728 B; wsc 'red' reuses buf post-compute)
// ============================================================================
__global__ void __launch_bounds__(512) kbig(
    const float* __restrict__ X, const float* __restrict__ ctx,
    const float* __restrict__ W, const float* __restrict__ clb,
    float* __restrict__ ws)
{
  extern __shared__ char smem[];
  float* xl  = (float*)(smem + 65536);
  float* red = (float*)smem;
  const int t = threadIdx.x;
  const int mg = blockIdx.x >> 5, s = blockIdx.x & 31;
  const int m0 = mg * 16, n0 = s * 8;

  const int lane = t & 63, w = t >> 6;
  const int wb = w * 32;
  const int l15 = lane & 15, lhi = lane >> 4;
  const char* clwb = (const char*)(ws + F_CLWB);

  // ---- slab loads FIRST (the long pole): thread t takes 16B chunk (t&255)
  // of rows (t>>8)+2i; row = 4KB contiguous bf16 ----
  const int p = t & 255, rh = t >> 8;
  bf16x8 sval[8];
#pragma unroll
  for (int i = 0; i < 8; ++i) {
    const int r = rh + 2 * i;
    sval[i] = *(const bf16x8*)(
        clwb + ((size_t)(m0 + r) * 65536 + (size_t)n0 * 256) * 2 + p * 16);
  }

  // af (ctx A-frags) + xl while slab loads fly
  bf16x8 af[2][8];
#pragma unroll
  for (int i = 0; i < 2; ++i)
#pragma unroll
    for (int c = 0; c < 8; ++c) {
      const float4* pc = (const float4*)(ctx + (wb + i * 16 + l15) * N +
                                         c * 32 + lhi * 8);
      af[i][c] = pack8(pc[0], pc[1]);
    }
  if (t < 256) {  // xl[nn][b] = X[b, n0+nn]
    const float4* xp = (const float4*)(X + t * N + n0);
    const float4 x0 = xp[0], x1 = xp[1];
    xl[0 * 256 + t] = x0.x; xl[1 * 256 + t] = x0.y;
    xl[2 * 256 + t] = x0.z; xl[3 * 256 + t] = x0.w;
    xl[4 * 256 + t] = x1.x; xl[5 * 256 + t] = x1.y;
    xl[6 * 256 + t] = x1.z; xl[7 * 256 + t] = x1.w;
  }

  // stage to LDS (16B chunks, row-XOR swizzle — same mapping as v14 reads)
#pragma unroll
  for (int i = 0; i < 8; ++i) {
    const int r = rh + 2 * i;
    *(bf16x8*)(smem + r * 4096 + ((p * 16) ^ ((r & 7) << 4))) = sval[i];
  }
  __syncthreads();

  const f32x4 zero = {0.f, 0.f, 0.f, 0.f};
  f32x4 acc[2];
  acc[0] = zero; acc[1] = zero;

#pragma unroll
  for (int n = 0; n < 8; ++n) {
    f32x4 h[2];
    h[0] = zero; h[1] = zero;
#pragma unroll
    for (int c = 0; c < 8; ++c) {
      const int kbyte = (n * 512 + ((c * 64 + lhi * 16) ^ ((l15 & 7) << 4)));
      bf16x8 bf = *(const bf16x8*)(smem + l15 * 4096 + kbyte);
      h[0] = mfma16(af[0][c], bf, h[0]);
      h[1] = mfma16(af[1][c], bf, h[1]);
    }
#pragma unroll
    for (int r = 0; r < 4; ++r) {
      h[0][r] *= xl[n * 256 + wb + lhi * 4 + r];
      h[1][r] *= xl[n * 256 + wb + 16 + lhi * 4 + r];
      acc[0][r] += h[0][r];
      acc[1][r] += h[1][r];
    }
  }

  // yadj partial: [block][256 b][16 ml] (coalesced)
  const size_t base = (size_t)blockIdx.x * 4096;
#pragma unroll
  for (int i = 0; i < 2; ++i)
#pragma unroll
    for (int r = 0; r < 4; ++r)
      ws[F_PART + base + (size_t)(wb + i * 16 + lhi * 4 + r) * 16 + l15] =
          acc[i][r];

  // wsc: colsum of W+CB for 8 j-columns, by mg==0 blocks (red reuses buf)
  if (mg == 0) {
    __syncthreads();
    if (t < 256) {
      const float4* wp = (const float4*)(W + t * N + s * 8);
      const float4* cp = (const float4*)(clb + t * N + s * 8);
      const float4 a0 = wp[0], a1 = wp[1], c0 = cp[0], c1 = cp[1];
      red[0 * 256 + t] = a0.x + c0.x; red[1 * 256 + t] = a0.y + c0.y;
      red[2 * 256 + t] = a0.z + c0.z; red[3 * 256 + t] = a0.w + c0.w;
      red[4 * 256 + t] = a1.x + c1.x; red[5 * 256 + t] = a1.y + c1.y;
      red[6 * 256 + t] = a1.z + c1.z; red[7 * 256 + t] = a1.w + c1.w;
    }
    __syncthreads();
    if (t < 64) {
      const int jj = t >> 3, seg = t & 7;
      float v = 0.f;
#pragma unroll
      for (int i = 0; i < 32; ++i) v += red[jj * 256 + seg * 32 + i];
      v += __shfl_xor(v, 1);
      v += __shfl_xor(v, 2);
      v += __shfl_xor(v, 4);
      if (seg == 0) ws[F_WSC + s * 8 + jj] = v;
    }
  }
}

// ============================================================================
// kred: yadj = sum over 32 s-slots; CS = sum over 16 kcvt slots -> bf16 CSB
// ============================================================================
__global__ void __launch_bounds__(256) kred(float* __restrict__ ws)
{
  const int o = blockIdx.x * 256 + threadIdx.x;
  const int b = o >> 8, m = o & 255;
  const int mgg = m >> 4, ml = m & 15;
  const size_t pb = F_PART + (size_t)(mgg * 32) * 4096 + (size_t)b * 16 + ml;
  float y = 0.f;
#pragma unroll
  for (int si = 0; si < 32; ++si)
    y += ws[pb + (size_t)si * 4096];
  ws[F_YADJ + o] = y;
  float cv = 0.f;
#pragma unroll
  for (int q = 0; q < 16; ++q)
    cv += ws[F_CSPART + q * 65536u + o];
  ((__bf16*)(ws + F_CSB))[o] = (__bf16)cv;
}

// ============================================================================
// kred2: SF[b,j] = wsc[j] + sum_k ctx[b,k]*CS[j,k]  (64 blocks, LDS-free)
// ============================================================================
__global__ void __launch_bounds__(256) kred2(
    const float* __restrict__ ctx, float* __restrict__ ws)
{
  const int t = threadIdx.x, blk = blockIdx.x;
  const int b0 = (blk >> 3) * 32, j0 = (blk & 7) * 32;
  const int lane = t & 63, w = t >> 6;
  const int l15 = lane & 15, lhi = lane >> 4;
  const int wqb = (w >> 1) * 16, wqj = (w & 1) * 16;
  const char* csb = (const char*)(ws + F_CSB);

  f32x4 accq = {0.f, 0.f, 0.f, 0.f};
#pragma unroll
  for (int c = 0; c < 8; ++c) {
    const float4* p = (const float4*)(ctx + (b0 + wqb + l15) * N +
                                      c * 32 + lhi * 8);
    bf16x8 a = pack8(p[0], p[1]);
    bf16x8 b = *(const bf16x8*)(csb + (j0 + wqj + l15) * 512 +
                                c * 64 + lhi * 16);
    accq = mfma16(a, b, accq);
  }
  const int j = j0 + wqj + l15;
  const float wscv = ws[F_WSC + j];
#pragma unroll
  for (int r = 0; r < 4; ++r) {
    const int b = b0 + wqb + lhi * 4 + r;
    ws[F_SFULL + b * N + j] = accq[r] + wscv;
  }
}

// ============================================================================
// kfin: unchanged (64 blocks, 2 fused K=256 MFMA chains + epilogue)
// ============================================================================
__global__ void __launch_bounds__(256) kfin(
    const float* __restrict__ X, const float* __restrict__ ctx,
    const float* __restrict__ W, const float* __restrict__ clb,
    const float* __restrict__ A, const float* __restrict__ scale,
    const int* __restrict__ tptr, float* __restrict__ out,
    float* __restrict__ ws)
{
  extern __shared__ char smem[];
  const int t = threadIdx.x, blk = blockIdx.x;
  const int b0 = (blk >> 3) * 32, k0 = (blk & 7) * 32;
  {
    const int row = t >> 3, q = t & 7;
    const int sw = (row & 7) << 4;
    const float4* sp = (const float4*)(ws + F_SFULL + (b0 + row) * N);
    const float4* xp = (const float4*)(X + (b0 + row) * N);
    const float4* wp = (const float4*)(W + (k0 + row) * N);
    const float4* cp = (const float4*)(clb + (k0 + row) * N);
#pragma unroll
    for (int i = 0; i < 8; ++i) {
      const int f4 = q * 8 + i;
      const int off = row * 512 + ((f4 * 8) ^ sw);
      *(bf16x4v*)(smem + off) = pack4(sp[f4]);
      *(bf16x4v*)(smem + 16384 + off) = pack4(xp[f4]);
      const float4 wv = wp[f4], cv = cp[f4];
      float4 s2;
      s2.x = wv.x + cv.x; s2.y = wv.y + cv.y;
      s2.z = wv.z + cv.z; s2.w = wv.w + cv.w;
      *(bf16x4v*)(smem + 49152 + off) = pack4(s2);
    }
    const float4* ap = (const float4*)(A + t * N + k0);
    char* at = smem + 32768;
#pragma unroll
    for (int i = 0; i < 8; ++i) {
      const float4 v = ap[i];
      const int kk = i * 4;
      *(__bf16*)(at + (kk + 0) * 512 + ((t * 2) ^ (((kk + 0) & 7) << 4))) = (__bf16)v.x;
      *(__bf16*)(at + (kk + 1) * 512 + ((t * 2) ^ (((kk + 1) & 7) << 4))) = (__bf16)v.y;
      *(__bf16*)(at + (kk + 2) * 512 + ((t * 2) ^ (((kk + 2) & 7) << 4))) = (__bf16)v.z;
      *(__bf16*)(at + (kk + 3) * 512 + ((t * 2) ^ (((kk + 3) & 7) << 4))) = (__bf16)v.w;
    }
  }
  __syncthreads();
  const int lane = t & 63, w = t >> 6;
  const int l15 = lane & 15, lhi = lane >> 4;
  const int wqb = (w >> 1) * 16, wqk = (w & 1) * 16;
  const int swz = (l15 & 7) << 4;
  f32x4 accd = {0.f, 0.f, 0.f, 0.f}, accw = {0.f, 0.f, 0.f, 0.f};
#pragma unroll
  for (int c = 0; c < 8; ++c) {
    const int kb = c * 64 + lhi * 16;
    bf16x8 as  = *(const bf16x8*)(smem + (wqb + l15) * 512 + (kb ^ swz));
    bf16x8 aat = *(const bf16x8*)(smem + 32768 + (wqk + l15) * 512 + (kb ^ swz));
    bf16x8 ax  = *(const bf16x8*)(smem + 16384 + (wqb + l15) * 512 + (kb ^ swz));
    bf16x8 awc = *(const bf16x8*)(smem + 49152 + (wqk + l15) * 512 + (kb ^ swz));
    accd = mfma16(as, aat, accd);
    accw = mfma16(ax, awc, accw);
  }
  const float sc = scale[0];
  const float tf = (float)(*tptr);
  const float c1 = tf / (tf + 1.f), c2 = 1.f / (tf + 1.f);
#pragma unroll
  for (int r = 0; r < 4; ++r) {
    const int b = b0 + wqb + lhi * 4 + r, k = k0 + wqk + l15;
    const int idx = b * N + k;
    const float xv = X[idx];
    out[idx] = sc * (xv * accd[r] - accw[r] - ws[F_YADJ + idx]);
    out[NN + idx] = ctx[idx] * c1 + xv * c2;
  }
}

extern "C" void kernel_launch(void* const* d_in, const int* in_sizes, int n_in,
                              void* d_out, int out_size, void* d_ws, size_t ws_size,
                              hipStream_t stream)
{
  (void)in_sizes; (void)n_in; (void)out_size;
  const float* X     = (const float*)d_in[0];
  const float* ctx   = (const float*)d_in[1];
  const float* W     = (const float*)d_in[2];
  const float* scale = (const float*)d_in[3];
  const float* A     = (const float*)d_in[4];
  const float* clw   = (const float*)d_in[5];
  const float* clb   = (const float*)d_in[6];
  const int*   tptr  = (const int*)d_in[7];
  float* out = (float*)d_out;
  float* ws  = (float*)d_ws;

  if (ws_size < (size_t)WS_FLOATS * sizeof(float)) return;

  (void)hipFuncSetAttribute((const void*)kbig,
                            hipFuncAttributeMaxDynamicSharedMemorySize, 73728);
  (void)hipFuncSetAttribute((const void*)kfin,
                            hipFuncAttributeMaxDynamicSharedMemorySize, 65536);

  kcvt<<<1024, 256, 0, stream>>>(clw, ws);
  kbig<<<512, 512, 73728, stream>>>(X, ctx, W, clb, ws);
  kred<<<256, 256, 0, stream>>>(ws);
  kred2<<<64, 256, 0, stream>>>(ctx, ws);
  kfin<<<64, 256, 65536, stream>>>(X, ctx, W, clb, A, scale, tptr, out, ws);
}